// Round 18
// baseline (93.932 us; speedup 1.0000x reference)
//
#include <hip/hip_runtime.h>

typedef short short8 __attribute__((ext_vector_type(8)));
typedef float f32x4 __attribute__((ext_vector_type(4)));

#define NN 8
#define CI 64
#define CO 128
#define HH 128
#define WW 128
#define PH 132             // padded (2-halo each side)
#define PW 132
#define MU 0.033333333333333333f

#define WS_W_BYTES (9 * 128 * 64 * 2)        // 147456
#define WS_T_OFF   WS_W_BYTES
#define WS_T_BYTES (NN * PH * PW * 4)        // 557568
#define WS_X_OFF   (WS_T_OFF + WS_T_BYTES)   // 705024
#define WS_X_BYTES ((size_t)NN * PH * PW * CI * 2)   // 17842176
#define WS_NB_OFF  (WS_X_OFF + WS_X_BYTES)   // 18547200
#define WS_TOTAL   (WS_NB_OFF + WS_T_BYTES)  // ~19.1 MB

__device__ __forceinline__ unsigned short f2bf(float f) {
  unsigned u = __float_as_uint(f);
  u += 0x7fffu + ((u >> 16) & 1u);     // round-to-nearest-even
  return (unsigned short)(u >> 16);
}

__device__ __forceinline__ void g2lds16(const void* g, void* l) {
  __builtin_amdgcn_global_load_lds(
      (const __attribute__((address_space(1))) unsigned int*)g,
      (__attribute__((address_space(3))) unsigned int*)l, 16, 0, 0);
}

// ================= FAST PATH =================
// prep: bf16 NHWC padded repack + channel-sum plane T + weights (coalesced
// layout: ws_w[(tap*16 + cb*2 + ks)*64 + lane] short8, lane=hi*16+lo holds
// w[co=cb*16+lo][ic=ks*32+hi*8+j], even taps only). ws_x is PLAIN NHWC
// [n][y][x][ic] bf16 (128 B per pixel; the lx XOR pair cancels).
__global__ __launch_bounds__(256) void prep_kernel(
    const float* __restrict__ in, const float* __restrict__ w,
    unsigned short* __restrict__ ws_w, float* __restrict__ ws_T,
    short8* __restrict__ ws_x) {
  const int b = blockIdx.x, tid = threadIdx.x;
  if (b < 512) {
    __shared__ short8 lx[256][8];            // [px][slot^(px&7)]
    const int n = b >> 6, pair = b & 63;
    const int px = tid;
    const int r = pair * 2 + (px >> 7), x = px & 127;
    const float* src = in + ((size_t)(n * CI) * HH + r) * WW + x;
    float tsum = 0.f;
    #pragma unroll
    for (int g = 0; g < 8; ++g) {
      short8 pk;
      #pragma unroll
      for (int j = 0; j < 8; ++j) {
        const float v = src[(size_t)(g * 8 + j) * (HH * WW)];
        tsum += v;
        pk[j] = (short)f2bf(v);
      }
      lx[px][g ^ (px & 7)] = pk;
    }
    ws_T[(n * PH + r + 2) * PW + (x + 2)] = tsum;
    __syncthreads();
    #pragma unroll
    for (int it = 0; it < 8; ++it) {         // coalesced NHWC store, 16B/lane
      const int G = it * 256 + tid;
      const int px2 = G >> 3, g2 = G & 7;
      const int r2 = pair * 2 + (px2 >> 7), x2 = px2 & 127;
      ws_x[((size_t)(n * PH + r2 + 2) * PW + (x2 + 2)) * 8 + g2] =
          lx[px2][g2 ^ (px2 & 7)];
    }
  } else if (b < 520) {                      // zero the padded borders
    const int n = b - 512;
    const short8 z = {0, 0, 0, 0, 0, 0, 0, 0};
    for (int e = tid; e < 1040 * 8; e += 256) {
      const int px = e >> 3, g = e & 7;
      int y, x;
      if (px < 528) { const int r4 = px / 132; y = (r4 < 2) ? r4 : r4 + 128; x = px - r4 * 132; }
      else { const int q = px - 528; const int c4 = q >> 7; x = (c4 < 2) ? c4 : c4 + 128; y = 2 + (q & 127); }
      ws_x[((size_t)(n * PH + y) * PW + x) * 8 + g] = z;
    }
    for (int e = tid; e < 1040; e += 256) {
      int y, x;
      if (e < 528) { const int r4 = e / 132; y = (r4 < 2) ? r4 : r4 + 128; x = e - r4 * 132; }
      else { const int q = e - 528; const int c4 = q >> 7; x = (c4 < 2) ? c4 : c4 + 128; y = 2 + (q & 127); }
      ws_T[(n * PH + y) * PW + x] = 0.f;
    }
  } else {                                   // weights, coalesced MFMA layout
    const int el = (b - 520) * 256 + tid;    // 0..9215 short8 elements
    const int lane = el & 63;
    const int idx = el >> 6;                 // 0..143 = tap*16 + cb*2 + ks
    const int ks = idx & 1, cb = (idx >> 1) & 7, tap = idx >> 4;
    const int lo = lane & 15, hi = lane >> 4;
    const int ky = (tap / 3) * 2, kx = (tap % 3) * 2;
    const float* wp = w + (size_t)((cb * 16 + lo) * 64 + ks * 32 + hi * 8) * 25
                        + ky * 5 + kx;
    short8 pk;
    #pragma unroll
    for (int j = 0; j < 8; ++j) pk[j] = (short)f2bf(wp[j * 25]);
    ((short8*)ws_w)[el] = pk;
  }
}

// nb: per-pixel neighbor plane, COMPACT [n][128][128] (16B-aligned reads)
__global__ __launch_bounds__(256) void nb_kernel(
    const float* __restrict__ ws_T, float* __restrict__ ws_nb) {
  const int p = blockIdx.x * 256 + threadIdx.x;   // 131072 interior pixels
  const int n = p >> 14, yx = p & 16383;
  const int y = yx >> 7, x = yx & 127;
  const float* Tb = ws_T + (size_t)(n * PH + y) * PW + x;
  float s = 0.f;
  #pragma unroll
  for (int ky = 0; ky < 5; ++ky)
    #pragma unroll
    for (int kx = 0; kx < 5; ++kx)
      if ((ky & 1) | (kx & 1)) s += Tb[ky * PW + kx];
  ws_nb[(size_t)p] = s * MU;
}

// conv v9: 4 waves/SIMD for latency hiding (the invariant all prior convs
// violated). Block = co-quarter x 8x32 unit; wave w = rows 2w,2w+1; ONLY
// the 36KB quarter-weights in LDS (shared by 4 waves); A-frags read direct
// from L2/L3-resident padded NHWC ws_x (no halo staging, no per-unit
// barrier). __launch_bounds__(256,4) -> VGPR<=128, live ~100, no spill.
// Grid = quarter*512 + unit: 512%8==0 so all 4 quarter-blocks of a unit
// land on the SAME XCD -> af L2-hot after first quarter touches it.
__global__ __launch_bounds__(256, 4) void conv_kernel(
    const unsigned short* __restrict__ ws_w, const float* __restrict__ ws_nb,
    const unsigned short* __restrict__ ws_x, float* __restrict__ out) {
  __shared__ short8 wl[36 * 64];       // 36864 B: [tap*4 + cbl*2 + ks][lane]

  const int tid = threadIdx.x;
  const int wave = tid >> 6, lane = tid & 63;
  const int lo = lane & 15, hi = lane >> 4;
  const int bid = blockIdx.x;          // 2048 = quarter*512 + unit
  const int quarter = bid >> 9;
  const int unit = bid & 511;
  const int n = unit >> 6, rem = unit & 63;
  const int ty0 = (rem >> 2) * 8, tx0 = (rem & 3) * 32;

  // stage quarter weights -> LDS (9 x 1KB chunks per wave)
  const short8* wsv = (const short8*)ws_w;
  for (int k = wave; k < 36; k += 4) {
    const short8* g = wsv + (((k >> 2) * 16 + quarter * 4 + (k & 3)) * 64 + lane);
    g2lds16(g, (char*)wl + k * 1024);
  }
  __syncthreads();                     // drains vmcnt (weights in LDS)

  const int voff = lo * 128 + hi * 16; // per-lane byte offset in a row-span

  // acc init from compact NB plane (rows=px after swapped MFMA)
  f32x4 acc[2][2][2];                  // [cbl][r][h]
  #pragma unroll
  for (int r = 0; r < 2; ++r)
    #pragma unroll
    for (int h = 0; h < 2; ++h) {
      const int gy = ty0 + wave * 2 + r;
      const f32x4 nbv = *(const f32x4*)&ws_nb[
          (size_t)((n * 128 + gy) * 128) + tx0 + h * 16 + hi * 4];
      acc[0][r][h] = nbv;
      acc[1][r][h] = nbv;
    }

  const char* base = (const char*)ws_x;
  #pragma unroll
  for (int tap = 0; tap < 9; ++tap) {
    const int ty = (tap / 3) * 2, tx = (tap % 3) * 2;
    #pragma unroll
    for (int ks = 0; ks < 2; ++ks) {
      const short8 wf0 = wl[(tap * 4 + 0 + ks) * 64 + lane];
      const short8 wf1 = wl[(tap * 4 + 2 + ks) * 64 + lane];
      #pragma unroll
      for (int r = 0; r < 2; ++r) {
        const int py = ty0 + wave * 2 + r + ty;    // padded input row
        #pragma unroll
        for (int h = 0; h < 2; ++h) {
          const short8 af = *(const short8*)(base
              + ((size_t)(n * PH + py) * PW + tx0 + h * 16 + tx) * 128
              + voff + ks * 64);
          acc[0][r][h] = __builtin_amdgcn_mfma_f32_16x16x32_bf16(
              af, wf0, acc[0][r][h], 0, 0, 0);
          acc[1][r][h] = __builtin_amdgcn_mfma_f32_16x16x32_bf16(
              af, wf1, acc[1][r][h], 0, 0, 0);
        }
      }
    }
  }

  // stores: h0+h1 cover full 128B lines; D row = px (hi*4+q), D col = co
  #pragma unroll
  for (int cbl = 0; cbl < 2; ++cbl)
    #pragma unroll
    for (int r = 0; r < 2; ++r)
      #pragma unroll
      for (int h = 0; h < 2; ++h) {
        const int co = quarter * 32 + cbl * 16 + lo;
        const int gy = ty0 + wave * 2 + r;
        const int gx = tx0 + h * 16 + hi * 4;
        *(f32x4*)&out[(((size_t)n * CO + co) * HH + gy) * WW + gx] =
            acc[cbl][r][h];
      }
}

// ================= SAFE PATH (Round-2 proven, 705 KB ws) =================
__global__ __launch_bounds__(256) void prep_kernel_safe(
    const float* __restrict__ in, const float* __restrict__ w,
    unsigned short* __restrict__ ws_w, float* __restrict__ ws_T) {
  const int bid = blockIdx.x, tid = threadIdx.x;
  if (bid < 288) {
    const int el = bid * 256 + tid;
    const int tap = el >> 13;
    const int rem = el & 8191;
    const int co = rem >> 6, ic = rem & 63;
    const int ky = (tap / 3) * 2, kx = (tap % 3) * 2;
    ws_w[el] = f2bf(w[(co * 64 + ic) * 25 + ky * 5 + kx]);
  } else {
    const int p = (bid - 288) * 256 + tid;
    const int n = p >> 14;
    const int yx = p & 16383;
    const float* base = in + (size_t)n * CI * (HH * WW) + yx;
    float s = 0.f;
    #pragma unroll
    for (int ic = 0; ic < CI; ++ic) s += base[ic * (HH * WW)];
    ws_T[p] = s;
  }
}

#define SHR 12
#define SHC 36
#define SNPOS (SHR * SHC)

__global__ __launch_bounds__(256, 2) void conv_kernel_safe(
    const float* __restrict__ in, const unsigned short* __restrict__ ws_w,
    const float* __restrict__ ws_T, float* __restrict__ out) {
  __shared__ short8 in_lds[SNPOS * 8];
  __shared__ float T_lds[SNPOS];

  const int tid = threadIdx.x;
  const int t = blockIdx.x;
  const int n = blockIdx.y;
  const int ty0 = (t >> 2) * 8;
  const int tx0 = (t & 3) * 32;

  for (int e = tid; e < SNPOS * 8; e += 256) {
    const int slot = e / SNPOS;
    const int pos = e - slot * SNPOS;
    const int r = pos / SHC, c = pos - r * SHC;
    const int gy = ty0 + r - 2, gx = tx0 + c - 2;
    const bool ok = (gy >= 0 && gy < HH && gx >= 0 && gx < WW);
    const long off = ((long)(n * CI + slot * 8) * HH + gy) * WW + gx;
    short8 pk;
    #pragma unroll
    for (int j = 0; j < 8; ++j) {
      const float v = ok ? in[off + (long)j * (HH * WW)] : 0.f;
      pk[j] = (short)f2bf(v);
    }
    in_lds[pos * 8 + (slot ^ (pos & 7))] = pk;
  }
  for (int e = tid; e < SNPOS; e += 256) {
    const int r = e / SHC, c = e - r * SHC;
    const int gy = ty0 + r - 2, gx = tx0 + c - 2;
    T_lds[e] = (gy >= 0 && gy < HH && gx >= 0 && gx < WW)
                   ? ws_T[((size_t)n * HH + gy) * WW + gx] : 0.f;
  }
  __syncthreads();

  const int wave = tid >> 6;
  const int lane = tid & 63;
  const int lo = lane & 15;
  const int hi = lane >> 4;

  int py[4], pxc[4];
  #pragma unroll
  for (int f = 0; f < 4; ++f) {
    const int pb = wave * 64 + f * 16;
    py[f] = pb >> 5;
    pxc[f] = (pb & 31) + lo;
  }

  f32x4 acc[8][4];
  #pragma unroll
  for (int cb = 0; cb < 8; ++cb)
    #pragma unroll
    for (int f = 0; f < 4; ++f) acc[cb][f] = (f32x4){0.f, 0.f, 0.f, 0.f};

  const short8* wsv = (const short8*)ws_w;

  #pragma unroll
  for (int tap = 0; tap < 9; ++tap) {
    const int ty = (tap / 3) * 2, tx = (tap % 3) * 2;
    #pragma unroll
    for (int ks = 0; ks < 2; ++ks) {
      short8 bfrag[4];
      #pragma unroll
      for (int f = 0; f < 4; ++f) {
        const int pos = (py[f] + ty) * SHC + (pxc[f] + tx);
        bfrag[f] = in_lds[pos * 8 + ((ks * 4 + hi) ^ (pos & 7))];
      }
      #pragma unroll
      for (int cb = 0; cb < 8; ++cb) {
        const short8 afrag = wsv[(tap * 128 + cb * 16 + lo) * 8 + ks * 4 + hi];
        #pragma unroll
        for (int f = 0; f < 4; ++f)
          acc[cb][f] = __builtin_amdgcn_mfma_f32_16x16x32_bf16(
              afrag, bfrag[f], acc[cb][f], 0, 0, 0);
      }
    }
  }

  float nb[4];
  #pragma unroll
  for (int f = 0; f < 4; ++f) {
    float s = 0.f;
    #pragma unroll
    for (int ky = 0; ky < 5; ++ky)
      #pragma unroll
      for (int kx = 0; kx < 5; ++kx)
        if ((ky & 1) | (kx & 1))
          s += T_lds[(py[f] + ky) * SHC + (pxc[f] + kx)];
    nb[f] = s * MU;
  }

  #pragma unroll
  for (int cb = 0; cb < 8; ++cb) {
    #pragma unroll
    for (int f = 0; f < 4; ++f) {
      const int gy = ty0 + py[f];
      const int gx = tx0 + pxc[f];
      #pragma unroll
      for (int q = 0; q < 4; ++q) {
        const int co = cb * 16 + hi * 4 + q;
        out[(((size_t)n * CO + co) * HH + gy) * WW + gx] = acc[cb][f][q] + nb[f];
      }
    }
  }
}

extern "C" void kernel_launch(void* const* d_in, const int* in_sizes, int n_in,
                              void* d_out, int out_size, void* d_ws, size_t ws_size,
                              hipStream_t stream) {
  const float* in = (const float*)d_in[0];
  const float* w  = (const float*)d_in[1];
  float* out = (float*)d_out;
  unsigned short* ws_w = (unsigned short*)d_ws;

  if (ws_size >= WS_TOTAL) {
    float* ws_T = (float*)((char*)d_ws + WS_T_OFF);
    short8* ws_x = (short8*)((char*)d_ws + WS_X_OFF);
    float* ws_nb = (float*)((char*)d_ws + WS_NB_OFF);
    prep_kernel<<<dim3(556), 256, 0, stream>>>(in, w, ws_w, ws_T, ws_x);
    nb_kernel<<<dim3(512), 256, 0, stream>>>(ws_T, ws_nb);
    conv_kernel<<<dim3(2048), 256, 0, stream>>>(
        ws_w, ws_nb, (const unsigned short*)ws_x, out);
  } else {
    float* ws_T = (float*)((char*)d_ws + WS_W_BYTES);
    prep_kernel_safe<<<dim3(288 + 512), 256, 0, stream>>>(in, w, ws_w, ws_T);
    conv_kernel_safe<<<dim3(64, NN), 256, 0, stream>>>(in, ws_w, ws_T, out);
  }
}

// Round 19
// 50.328 us; speedup vs baseline: 1.8664x; 1.8664x over previous
//
#include <hip/hip_runtime.h>

typedef short short8 __attribute__((ext_vector_type(8)));
typedef float f32x4 __attribute__((ext_vector_type(4)));

#define NN 8
#define CI 64
#define CO 128
#define HH 128
#define WW 128
#define PH 132             // padded (2-halo each side)
#define PW 132
#define MU 0.033333333333333333f

#define WS_W_BYTES (9 * 128 * 64 * 2)        // 147456
#define WS_T_OFF   WS_W_BYTES
#define WS_T_BYTES (NN * PH * PW * 4)        // 557568
#define WS_X_OFF   (WS_T_OFF + WS_T_BYTES)   // 705024
#define WS_X_BYTES ((size_t)NN * PH * PW * CI * 2)   // 17842176
#define WS_NB_OFF  (WS_X_OFF + WS_X_BYTES)   // 18547200
#define WS_TOTAL   (WS_NB_OFF + WS_T_BYTES)  // ~19.1 MB

__device__ __forceinline__ unsigned short f2bf(float f) {
  unsigned u = __float_as_uint(f);
  u += 0x7fffu + ((u >> 16) & 1u);     // round-to-nearest-even
  return (unsigned short)(u >> 16);
}

__device__ __forceinline__ void g2lds16(const void* g, void* l) {
  __builtin_amdgcn_global_load_lds(
      (const __attribute__((address_space(1))) unsigned int*)g,
      (__attribute__((address_space(3))) unsigned int*)l, 16, 0, 0);
}
__device__ __forceinline__ void g2lds4(const void* g, void* l) {
  __builtin_amdgcn_global_load_lds(
      (const __attribute__((address_space(1))) unsigned int*)g,
      (__attribute__((address_space(3))) unsigned int*)l, 4, 0, 0);
}

// ================= FAST PATH =================
// prep: bf16 NHWC padded repack + channel-sum plane T + weights (coalesced
// layout: ws_w[(tap*16 + cb*2 + ks)*64 + lane] short8, lane=hi*16+lo holds
// w[co=cb*16+lo][ic=ks*32+hi*8+j], even taps only). ws_x is PLAIN NHWC
// [n][y][x][ic] bf16 (128 B per pixel; the lx XOR pair cancels).
__global__ __launch_bounds__(256) void prep_kernel(
    const float* __restrict__ in, const float* __restrict__ w,
    unsigned short* __restrict__ ws_w, float* __restrict__ ws_T,
    short8* __restrict__ ws_x) {
  const int b = blockIdx.x, tid = threadIdx.x;
  if (b < 512) {
    __shared__ short8 lx[256][8];            // [px][slot^(px&7)]
    const int n = b >> 6, pair = b & 63;
    const int px = tid;
    const int r = pair * 2 + (px >> 7), x = px & 127;
    const float* src = in + ((size_t)(n * CI) * HH + r) * WW + x;
    float tsum = 0.f;
    #pragma unroll
    for (int g = 0; g < 8; ++g) {
      short8 pk;
      #pragma unroll
      for (int j = 0; j < 8; ++j) {
        const float v = src[(size_t)(g * 8 + j) * (HH * WW)];
        tsum += v;
        pk[j] = (short)f2bf(v);
      }
      lx[px][g ^ (px & 7)] = pk;
    }
    ws_T[(n * PH + r + 2) * PW + (x + 2)] = tsum;
    __syncthreads();
    #pragma unroll
    for (int it = 0; it < 8; ++it) {         // coalesced NHWC store, 16B/lane
      const int G = it * 256 + tid;
      const int px2 = G >> 3, g2 = G & 7;
      const int r2 = pair * 2 + (px2 >> 7), x2 = px2 & 127;
      ws_x[((size_t)(n * PH + r2 + 2) * PW + (x2 + 2)) * 8 + g2] =
          lx[px2][g2 ^ (px2 & 7)];
    }
  } else if (b < 520) {                      // zero the padded borders
    const int n = b - 512;
    const short8 z = {0, 0, 0, 0, 0, 0, 0, 0};
    for (int e = tid; e < 1040 * 8; e += 256) {
      const int px = e >> 3, g = e & 7;
      int y, x;
      if (px < 528) { const int r4 = px / 132; y = (r4 < 2) ? r4 : r4 + 128; x = px - r4 * 132; }
      else { const int q = px - 528; const int c4 = q >> 7; x = (c4 < 2) ? c4 : c4 + 128; y = 2 + (q & 127); }
      ws_x[((size_t)(n * PH + y) * PW + x) * 8 + g] = z;
    }
    for (int e = tid; e < 1040; e += 256) {
      int y, x;
      if (e < 528) { const int r4 = e / 132; y = (r4 < 2) ? r4 : r4 + 128; x = e - r4 * 132; }
      else { const int q = e - 528; const int c4 = q >> 7; x = (c4 < 2) ? c4 : c4 + 128; y = 2 + (q & 127); }
      ws_T[(n * PH + y) * PW + x] = 0.f;
    }
  } else {                                   // weights, coalesced MFMA layout
    const int el = (b - 520) * 256 + tid;    // 0..9215 short8 elements
    const int lane = el & 63;
    const int idx = el >> 6;                 // 0..143 = tap*16 + cb*2 + ks
    const int ks = idx & 1, cb = (idx >> 1) & 7, tap = idx >> 4;
    const int lo = lane & 15, hi = lane >> 4;
    const int ky = (tap / 3) * 2, kx = (tap % 3) * 2;
    const float* wp = w + (size_t)((cb * 16 + lo) * 64 + ks * 32 + hi * 8) * 25
                        + ky * 5 + kx;
    short8 pk;
    #pragma unroll
    for (int j = 0; j < 8; ++j) pk[j] = (short)f2bf(wp[j * 25]);
    ((short8*)ws_w)[el] = pk;
  }
}

// nb: per-pixel neighbor plane, COMPACT [n][128][128] (16B-aligned reads)
__global__ __launch_bounds__(256) void nb_kernel(
    const float* __restrict__ ws_T, float* __restrict__ ws_nb) {
  const int p = blockIdx.x * 256 + threadIdx.x;   // 131072 interior pixels
  const int n = p >> 14, yx = p & 16383;
  const int y = yx >> 7, x = yx & 127;
  const float* Tb = ws_T + (size_t)(n * PH + y) * PW + x;
  float s = 0.f;
  #pragma unroll
  for (int ky = 0; ky < 5; ++ky)
    #pragma unroll
    for (int kx = 0; kx < 5; ++kx)
      if ((ky & 1) | (kx & 1)) s += Tb[ky * PW + kx];
  ws_nb[(size_t)p] = s * MU;
}

// conv v10: R13's measured-best structure (4x32 unit, 4 units/block, halo+
// quarter-weights in LDS, 73.7KB -> 2 blocks/CU) + HAND-WRITTEN 3-deep
// software pipeline: 18 (tap,ks) steps fully unrolled over named register
// sets A/B/C, each set's 4 ds_read_b128 issued 2 steps before its 4 MFMAs
// (~8 reads in flight/wave covers the ~120cyc LDS latency that R18's
// VGPR=52 proved the compiler never hides on its own).
__global__ __launch_bounds__(256, 2) void conv_kernel(
    const unsigned short* __restrict__ ws_w, const float* __restrict__ ws_nb,
    const unsigned short* __restrict__ ws_x, float* __restrict__ out) {
  __shared__ short8 halo[288 * 8];     // 36864 B: 8 rows x 36 cols, swizzled
  __shared__ short8 wl[36 * 64];       // 36864 B: [tap*4 + cbl*2 + ks][lane]
  __shared__ float  nbt[128];          // 512 B: 4 rows x 32 cols

  const int tid = threadIdx.x;
  const int wave = tid >> 6, lane = tid & 63;
  const int bid = blockIdx.x;          // 1024
  const int cob = bid >> 8;            // 0..3: 32-co quarter
  const int s   = bid & 255;           // spatial set (4 units each)
  const int lo = lane & 15, hi = lane >> 4;

  // stage this quarter's weights once (first unit's syncthreads drains)
  const short8* wsv = (const short8*)ws_w;
  for (int k = wave; k < 36; k += 4) {
    const int tap = k >> 2, r = k & 3;       // r = cbl*2 + ks
    const short8* g = wsv + ((tap * 16 + cob * 4 + r) * 64 + lane);
    g2lds16(g, (char*)wl + k * 1024);
  }

  for (int j = 0; j < 4; ++j) {
    const int su = s * 4 + j;                // 0..1023
    const int n = su >> 7, rem = su & 127;
    const int ty0 = (rem >> 2) * 4;          // 32 y-units of 4 rows
    const int tx0 = (rem & 3) * 32;          // 4 x-units of 32 cols

    // halo DMA: 36 x 1KB chunks (9 per wave), source pre-swizzled
    for (int k = wave; k < 36; k += 4) {
      const int pos = k * 8 + (lane >> 3);
      const int r = pos / 36, c = pos - r * 36;
      const int chunk = (lane & 7) ^ (pos & 7);
      const unsigned short* g =
          ws_x + ((size_t)(n * PH + ty0 + r) * PW + (tx0 + c)) * 64 + chunk * 8;
      g2lds16(g, (char*)halo + k * 1024);
    }
    if (wave < 2) {                          // nb tile (compact plane)
      const float* g = ws_nb
          + (size_t)((n * 128 + ty0 + 2 * wave + (lane >> 5)) * 128)
          + tx0 + (lane & 31);
      g2lds4(g, (char*)nbt + wave * 256);
    }
    __syncthreads();                         // drains vmcnt (DMA complete)

    // acc init from NB (rows=px after operand swap); wave owns row `wave`
    const f32x4 nbv0 = *(const f32x4*)&nbt[wave * 32 + 0  + hi * 4];
    const f32x4 nbv1 = *(const f32x4*)&nbt[wave * 32 + 16 + hi * 4];
    f32x4 acc00 = nbv0, acc01 = nbv1;        // cbl0: h0, h1
    f32x4 acc10 = nbv0, acc11 = nbv1;        // cbl1: h0, h1

    short8 Aaf0, Aaf1, Awf0, Awf1;
    short8 Baf0, Baf1, Bwf0, Bwf1;
    short8 Caf0, Caf1, Cwf0, Cwf1;

#define LOADSET(P, K) { \
      constexpr int tap_ = (K) >> 1, ks_ = (K) & 1; \
      constexpr int ty_ = (tap_ / 3) * 2, tx_ = (tap_ % 3) * 2; \
      const int p0_ = (wave + ty_) * 36 + (lo + tx_); \
      const int p1_ = p0_ + 16; \
      P##af0 = halo[p0_ * 8 + ((ks_ * 4 + hi) ^ (p0_ & 7))]; \
      P##af1 = halo[p1_ * 8 + ((ks_ * 4 + hi) ^ (p1_ & 7))]; \
      P##wf0 = wl[(tap_ * 4 + 0 + ks_) * 64 + lane]; \
      P##wf1 = wl[(tap_ * 4 + 2 + ks_) * 64 + lane]; \
    }
#define MFMASET(P) \
    acc00 = __builtin_amdgcn_mfma_f32_16x16x32_bf16(P##af0, P##wf0, acc00, 0, 0, 0); \
    acc01 = __builtin_amdgcn_mfma_f32_16x16x32_bf16(P##af1, P##wf0, acc01, 0, 0, 0); \
    acc10 = __builtin_amdgcn_mfma_f32_16x16x32_bf16(P##af0, P##wf1, acc10, 0, 0, 0); \
    acc11 = __builtin_amdgcn_mfma_f32_16x16x32_bf16(P##af1, P##wf1, acc11, 0, 0, 0);

    LOADSET(A, 0); LOADSET(B, 1);
    LOADSET(C, 2);  MFMASET(A);
    LOADSET(A, 3);  MFMASET(B);
    LOADSET(B, 4);  MFMASET(C);
    LOADSET(C, 5);  MFMASET(A);
    LOADSET(A, 6);  MFMASET(B);
    LOADSET(B, 7);  MFMASET(C);
    LOADSET(C, 8);  MFMASET(A);
    LOADSET(A, 9);  MFMASET(B);
    LOADSET(B, 10); MFMASET(C);
    LOADSET(C, 11); MFMASET(A);
    LOADSET(A, 12); MFMASET(B);
    LOADSET(B, 13); MFMASET(C);
    LOADSET(C, 14); MFMASET(A);
    LOADSET(A, 15); MFMASET(B);
    LOADSET(B, 16); MFMASET(C);
    LOADSET(C, 17); MFMASET(A);
    MFMASET(B);
    MFMASET(C);
#undef LOADSET
#undef MFMASET

    // stores: h0+h1 cover the full 32-px row -> whole 128B lines per block
    {
      const int gy = ty0 + wave;
      const int gx0 = tx0 + hi * 4;
      const int co0 = cob * 32 + lo;
      *(f32x4*)&out[(((size_t)n * CO + co0) * HH + gy) * WW + gx0] = acc00;
      *(f32x4*)&out[(((size_t)n * CO + co0) * HH + gy) * WW + gx0 + 16] = acc01;
      *(f32x4*)&out[(((size_t)n * CO + co0 + 16) * HH + gy) * WW + gx0] = acc10;
      *(f32x4*)&out[(((size_t)n * CO + co0 + 16) * HH + gy) * WW + gx0 + 16] = acc11;
    }
    __syncthreads();                         // protect halo/nbt overwrite
  }
}

// ================= SAFE PATH (Round-2 proven, 705 KB ws) =================
__global__ __launch_bounds__(256) void prep_kernel_safe(
    const float* __restrict__ in, const float* __restrict__ w,
    unsigned short* __restrict__ ws_w, float* __restrict__ ws_T) {
  const int bid = blockIdx.x, tid = threadIdx.x;
  if (bid < 288) {
    const int el = bid * 256 + tid;
    const int tap = el >> 13;
    const int rem = el & 8191;
    const int co = rem >> 6, ic = rem & 63;
    const int ky = (tap / 3) * 2, kx = (tap % 3) * 2;
    ws_w[el] = f2bf(w[(co * 64 + ic) * 25 + ky * 5 + kx]);
  } else {
    const int p = (bid - 288) * 256 + tid;
    const int n = p >> 14;
    const int yx = p & 16383;
    const float* base = in + (size_t)n * CI * (HH * WW) + yx;
    float s = 0.f;
    #pragma unroll
    for (int ic = 0; ic < CI; ++ic) s += base[ic * (HH * WW)];
    ws_T[p] = s;
  }
}

#define SHR 12
#define SHC 36
#define SNPOS (SHR * SHC)

__global__ __launch_bounds__(256, 2) void conv_kernel_safe(
    const float* __restrict__ in, const unsigned short* __restrict__ ws_w,
    const float* __restrict__ ws_T, float* __restrict__ out) {
  __shared__ short8 in_lds[SNPOS * 8];
  __shared__ float T_lds[SNPOS];

  const int tid = threadIdx.x;
  const int t = blockIdx.x;
  const int n = blockIdx.y;
  const int ty0 = (t >> 2) * 8;
  const int tx0 = (t & 3) * 32;

  for (int e = tid; e < SNPOS * 8; e += 256) {
    const int slot = e / SNPOS;
    const int pos = e - slot * SNPOS;
    const int r = pos / SHC, c = pos - r * SHC;
    const int gy = ty0 + r - 2, gx = tx0 + c - 2;
    const bool ok = (gy >= 0 && gy < HH && gx >= 0 && gx < WW);
    const long off = ((long)(n * CI + slot * 8) * HH + gy) * WW + gx;
    short8 pk;
    #pragma unroll
    for (int j = 0; j < 8; ++j) {
      const float v = ok ? in[off + (long)j * (HH * WW)] : 0.f;
      pk[j] = (short)f2bf(v);
    }
    in_lds[pos * 8 + (slot ^ (pos & 7))] = pk;
  }
  for (int e = tid; e < SNPOS; e += 256) {
    const int r = e / SHC, c = e - r * SHC;
    const int gy = ty0 + r - 2, gx = tx0 + c - 2;
    T_lds[e] = (gy >= 0 && gy < HH && gx >= 0 && gx < WW)
                   ? ws_T[((size_t)n * HH + gy) * WW + gx] : 0.f;
  }
  __syncthreads();

  const int wave = tid >> 6;
  const int lane = tid & 63;
  const int lo = lane & 15;
  const int hi = lane >> 4;

  int py[4], pxc[4];
  #pragma unroll
  for (int f = 0; f < 4; ++f) {
    const int pb = wave * 64 + f * 16;
    py[f] = pb >> 5;
    pxc[f] = (pb & 31) + lo;
  }

  f32x4 acc[8][4];
  #pragma unroll
  for (int cb = 0; cb < 8; ++cb)
    #pragma unroll
    for (int f = 0; f < 4; ++f) acc[cb][f] = (f32x4){0.f, 0.f, 0.f, 0.f};

  const short8* wsv = (const short8*)ws_w;

  #pragma unroll
  for (int tap = 0; tap < 9; ++tap) {
    const int ty = (tap / 3) * 2, tx = (tap % 3) * 2;
    #pragma unroll
    for (int ks = 0; ks < 2; ++ks) {
      short8 bfrag[4];
      #pragma unroll
      for (int f = 0; f < 4; ++f) {
        const int pos = (py[f] + ty) * SHC + (pxc[f] + tx);
        bfrag[f] = in_lds[pos * 8 + ((ks * 4 + hi) ^ (pos & 7))];
      }
      #pragma unroll
      for (int cb = 0; cb < 8; ++cb) {
        const short8 afrag = wsv[(tap * 128 + cb * 16 + lo) * 8 + ks * 4 + hi];
        #pragma unroll
        for (int f = 0; f < 4; ++f)
          acc[cb][f] = __builtin_amdgcn_mfma_f32_16x16x32_bf16(
              afrag, bfrag[f], acc[cb][f], 0, 0, 0);
      }
    }
  }

  float nb[4];
  #pragma unroll
  for (int f = 0; f < 4; ++f) {
    float s = 0.f;
    #pragma unroll
    for (int ky = 0; ky < 5; ++ky)
      #pragma unroll
      for (int kx = 0; kx < 5; ++kx)
        if ((ky & 1) | (kx & 1))
          s += T_lds[(py[f] + ky) * SHC + (pxc[f] + kx)];
    nb[f] = s * MU;
  }

  #pragma unroll
  for (int cb = 0; cb < 8; ++cb) {
    #pragma unroll
    for (int f = 0; f < 4; ++f) {
      const int gy = ty0 + py[f];
      const int gx = tx0 + pxc[f];
      #pragma unroll
      for (int q = 0; q < 4; ++q) {
        const int co = cb * 16 + hi * 4 + q;
        out[(((size_t)n * CO + co) * HH + gy) * WW + gx] = acc[cb][f][q] + nb[f];
      }
    }
  }
}

extern "C" void kernel_launch(void* const* d_in, const int* in_sizes, int n_in,
                              void* d_out, int out_size, void* d_ws, size_t ws_size,
                              hipStream_t stream) {
  const float* in = (const float*)d_in[0];
  const float* w  = (const float*)d_in[1];
  float* out = (float*)d_out;
  unsigned short* ws_w = (unsigned short*)d_ws;

  if (ws_size >= WS_TOTAL) {
    float* ws_T = (float*)((char*)d_ws + WS_T_OFF);
    short8* ws_x = (short8*)((char*)d_ws + WS_X_OFF);
    float* ws_nb = (float*)((char*)d_ws + WS_NB_OFF);
    prep_kernel<<<dim3(556), 256, 0, stream>>>(in, w, ws_w, ws_T, ws_x);
    nb_kernel<<<dim3(512), 256, 0, stream>>>(ws_T, ws_nb);
    conv_kernel<<<dim3(1024), 256, 0, stream>>>(
        ws_w, ws_nb, (const unsigned short*)ws_x, out);
  } else {
    float* ws_T = (float*)((char*)d_ws + WS_W_BYTES);
    prep_kernel_safe<<<dim3(288 + 512), 256, 0, stream>>>(in, w, ws_w, ws_T);
    conv_kernel_safe<<<dim3(64, NN), 256, 0, stream>>>(in, ws_w, ws_T, out);
  }
}

// Round 20
// 45.556 us; speedup vs baseline: 2.0619x; 1.1048x over previous
//
#include <hip/hip_runtime.h>

typedef short short8 __attribute__((ext_vector_type(8)));
typedef float f32x4 __attribute__((ext_vector_type(4)));

#define NN 8
#define CI 64
#define CO 128
#define HH 128
#define WW 128
#define PH 132             // padded (2-halo each side)
#define PW 132
#define MU 0.033333333333333333f

#define WS_W_BYTES (9 * 128 * 64 * 2)        // 147456
#define WS_T_OFF   WS_W_BYTES
#define WS_T_BYTES (NN * PH * PW * 4)        // 557568
#define WS_X_OFF   (WS_T_OFF + WS_T_BYTES)   // 705024
#define WS_X_BYTES ((size_t)NN * PH * PW * CI * 2)   // 17842176
#define WS_NB_OFF  (WS_X_OFF + WS_X_BYTES)   // 18547200
#define WS_TOTAL   (WS_NB_OFF + WS_T_BYTES)  // ~19.1 MB

__device__ __forceinline__ unsigned short f2bf(float f) {
  unsigned u = __float_as_uint(f);
  u += 0x7fffu + ((u >> 16) & 1u);     // round-to-nearest-even
  return (unsigned short)(u >> 16);
}

__device__ __forceinline__ void g2lds16(const void* g, void* l) {
  __builtin_amdgcn_global_load_lds(
      (const __attribute__((address_space(1))) unsigned int*)g,
      (__attribute__((address_space(3))) unsigned int*)l, 16, 0, 0);
}
__device__ __forceinline__ void g2lds4(const void* g, void* l) {
  __builtin_amdgcn_global_load_lds(
      (const __attribute__((address_space(1))) unsigned int*)g,
      (__attribute__((address_space(3))) unsigned int*)l, 4, 0, 0);
}

// ================= FAST PATH =================
// prep: bf16 NHWC padded repack + channel-sum plane T + weights (coalesced
// layout: ws_w[(tap*16 + cb*2 + ks)*64 + lane] short8, lane=hi*16+lo holds
// w[co=cb*16+lo][ic=ks*32+hi*8+j], even taps only). ws_x is PLAIN NHWC
// [n][y][x][ic] bf16 (128 B per pixel; the lx XOR pair cancels).
__global__ __launch_bounds__(256) void prep_kernel(
    const float* __restrict__ in, const float* __restrict__ w,
    unsigned short* __restrict__ ws_w, float* __restrict__ ws_T,
    short8* __restrict__ ws_x) {
  const int b = blockIdx.x, tid = threadIdx.x;
  if (b < 512) {
    __shared__ short8 lx[256][8];            // [px][slot^(px&7)]
    const int n = b >> 6, pair = b & 63;
    const int px = tid;
    const int r = pair * 2 + (px >> 7), x = px & 127;
    const float* src = in + ((size_t)(n * CI) * HH + r) * WW + x;
    float tsum = 0.f;
    #pragma unroll
    for (int g = 0; g < 8; ++g) {
      short8 pk;
      #pragma unroll
      for (int j = 0; j < 8; ++j) {
        const float v = src[(size_t)(g * 8 + j) * (HH * WW)];
        tsum += v;
        pk[j] = (short)f2bf(v);
      }
      lx[px][g ^ (px & 7)] = pk;
    }
    ws_T[(n * PH + r + 2) * PW + (x + 2)] = tsum;
    __syncthreads();
    #pragma unroll
    for (int it = 0; it < 8; ++it) {         // coalesced NHWC store, 16B/lane
      const int G = it * 256 + tid;
      const int px2 = G >> 3, g2 = G & 7;
      const int r2 = pair * 2 + (px2 >> 7), x2 = px2 & 127;
      ws_x[((size_t)(n * PH + r2 + 2) * PW + (x2 + 2)) * 8 + g2] =
          lx[px2][g2 ^ (px2 & 7)];
    }
  } else if (b < 520) {                      // zero the padded borders
    const int n = b - 512;
    const short8 z = {0, 0, 0, 0, 0, 0, 0, 0};
    for (int e = tid; e < 1040 * 8; e += 256) {
      const int px = e >> 3, g = e & 7;
      int y, x;
      if (px < 528) { const int r4 = px / 132; y = (r4 < 2) ? r4 : r4 + 128; x = px - r4 * 132; }
      else { const int q = px - 528; const int c4 = q >> 7; x = (c4 < 2) ? c4 : c4 + 128; y = 2 + (q & 127); }
      ws_x[((size_t)(n * PH + y) * PW + x) * 8 + g] = z;
    }
    for (int e = tid; e < 1040; e += 256) {
      int y, x;
      if (e < 528) { const int r4 = e / 132; y = (r4 < 2) ? r4 : r4 + 128; x = e - r4 * 132; }
      else { const int q = e - 528; const int c4 = q >> 7; x = (c4 < 2) ? c4 : c4 + 128; y = 2 + (q & 127); }
      ws_T[(n * PH + y) * PW + x] = 0.f;
    }
  } else {                                   // weights, coalesced MFMA layout
    const int el = (b - 520) * 256 + tid;    // 0..9215 short8 elements
    const int lane = el & 63;
    const int idx = el >> 6;                 // 0..143 = tap*16 + cb*2 + ks
    const int ks = idx & 1, cb = (idx >> 1) & 7, tap = idx >> 4;
    const int lo = lane & 15, hi = lane >> 4;
    const int ky = (tap / 3) * 2, kx = (tap % 3) * 2;
    const float* wp = w + (size_t)((cb * 16 + lo) * 64 + ks * 32 + hi * 8) * 25
                        + ky * 5 + kx;
    short8 pk;
    #pragma unroll
    for (int j = 0; j < 8; ++j) pk[j] = (short)f2bf(wp[j * 25]);
    ((short8*)ws_w)[el] = pk;
  }
}

// nb: per-pixel neighbor plane, COMPACT [n][128][128] (16B-aligned reads)
__global__ __launch_bounds__(256) void nb_kernel(
    const float* __restrict__ ws_T, float* __restrict__ ws_nb) {
  const int p = blockIdx.x * 256 + threadIdx.x;   // 131072 interior pixels
  const int n = p >> 14, yx = p & 16383;
  const int y = yx >> 7, x = yx & 127;
  const float* Tb = ws_T + (size_t)(n * PH + y) * PW + x;
  float s = 0.f;
  #pragma unroll
  for (int ky = 0; ky < 5; ++ky)
    #pragma unroll
    for (int kx = 0; kx < 5; ++kx)
      if ((ky & 1) | (kx & 1)) s += Tb[ky * PW + kx];
  ws_nb[(size_t)p] = s * MU;
}

// conv v11: v10's exact body (3-deep pipelined 4x32 units, halo+quarter-
// weights in LDS, 73.7KB -> 2 blocks/CU) with the WORK->BLOCK MAP remade
// for memory locality:
//  - n = bid&7  -> all blocks of image n land on XCD n (round-robin
//    heuristic) so ws_x[n] (2.2MB) is XCD-L2-resident for every reader;
//  - block owns a 4-row x 128-col x 32-co strip and loops x-subtiles, so
//    it COMPLETES whole 512B output rows (2KB per co) instead of leaving
//    128B fragments to temporally-distant blocks (DRAM page locality).
__global__ __launch_bounds__(256, 2) void conv_kernel(
    const unsigned short* __restrict__ ws_w, const float* __restrict__ ws_nb,
    const unsigned short* __restrict__ ws_x, float* __restrict__ out) {
  __shared__ short8 halo[288 * 8];     // 36864 B: 8 rows x 36 cols, swizzled
  __shared__ short8 wl[36 * 64];       // 36864 B: [tap*4 + cbl*2 + ks][lane]
  __shared__ float  nbt[128];          // 512 B: 4 rows x 32 cols

  const int tid = threadIdx.x;
  const int wave = tid >> 6, lane = tid & 63;
  const int bid = blockIdx.x;          // 1024 = (strip*4 + quarter)*8 + n
  const int n = bid & 7;
  const int rest = bid >> 3;
  const int cob = rest & 3;            // co-quarter
  const int ty0 = (rest >> 2) * 4;     // 32 y-strips of 4 rows
  const int lo = lane & 15, hi = lane >> 4;

  // stage this quarter's weights once (first unit's syncthreads drains)
  const short8* wsv = (const short8*)ws_w;
  for (int k = wave; k < 36; k += 4) {
    const int tap = k >> 2, r = k & 3;       // r = cbl*2 + ks
    const short8* g = wsv + ((tap * 16 + cob * 4 + r) * 64 + lane);
    g2lds16(g, (char*)wl + k * 1024);
  }

  for (int j = 0; j < 4; ++j) {
    const int tx0 = j * 32;                  // x-subtiles of our 4-row strip

    // halo DMA: 36 x 1KB chunks (9 per wave), source pre-swizzled
    for (int k = wave; k < 36; k += 4) {
      const int pos = k * 8 + (lane >> 3);
      const int r = pos / 36, c = pos - r * 36;
      const int chunk = (lane & 7) ^ (pos & 7);
      const unsigned short* g =
          ws_x + ((size_t)(n * PH + ty0 + r) * PW + (tx0 + c)) * 64 + chunk * 8;
      g2lds16(g, (char*)halo + k * 1024);
    }
    if (wave < 2) {                          // nb tile (compact plane)
      const float* g = ws_nb
          + (size_t)((n * 128 + ty0 + 2 * wave + (lane >> 5)) * 128)
          + tx0 + (lane & 31);
      g2lds4(g, (char*)nbt + wave * 256);
    }
    __syncthreads();                         // drains vmcnt (DMA complete)

    // acc init from NB (rows=px after operand swap); wave owns row `wave`
    const f32x4 nbv0 = *(const f32x4*)&nbt[wave * 32 + 0  + hi * 4];
    const f32x4 nbv1 = *(const f32x4*)&nbt[wave * 32 + 16 + hi * 4];
    f32x4 acc00 = nbv0, acc01 = nbv1;        // cbl0: h0, h1
    f32x4 acc10 = nbv0, acc11 = nbv1;        // cbl1: h0, h1

    short8 Aaf0, Aaf1, Awf0, Awf1;
    short8 Baf0, Baf1, Bwf0, Bwf1;
    short8 Caf0, Caf1, Cwf0, Cwf1;

#define LOADSET(P, K) { \
      constexpr int tap_ = (K) >> 1, ks_ = (K) & 1; \
      constexpr int ty_ = (tap_ / 3) * 2, tx_ = (tap_ % 3) * 2; \
      const int p0_ = (wave + ty_) * 36 + (lo + tx_); \
      const int p1_ = p0_ + 16; \
      P##af0 = halo[p0_ * 8 + ((ks_ * 4 + hi) ^ (p0_ & 7))]; \
      P##af1 = halo[p1_ * 8 + ((ks_ * 4 + hi) ^ (p1_ & 7))]; \
      P##wf0 = wl[(tap_ * 4 + 0 + ks_) * 64 + lane]; \
      P##wf1 = wl[(tap_ * 4 + 2 + ks_) * 64 + lane]; \
    }
#define MFMASET(P) \
    acc00 = __builtin_amdgcn_mfma_f32_16x16x32_bf16(P##af0, P##wf0, acc00, 0, 0, 0); \
    acc01 = __builtin_amdgcn_mfma_f32_16x16x32_bf16(P##af1, P##wf0, acc01, 0, 0, 0); \
    acc10 = __builtin_amdgcn_mfma_f32_16x16x32_bf16(P##af0, P##wf1, acc10, 0, 0, 0); \
    acc11 = __builtin_amdgcn_mfma_f32_16x16x32_bf16(P##af1, P##wf1, acc11, 0, 0, 0);

    LOADSET(A, 0); LOADSET(B, 1);
    LOADSET(C, 2);  MFMASET(A);
    LOADSET(A, 3);  MFMASET(B);
    LOADSET(B, 4);  MFMASET(C);
    LOADSET(C, 5);  MFMASET(A);
    LOADSET(A, 6);  MFMASET(B);
    LOADSET(B, 7);  MFMASET(C);
    LOADSET(C, 8);  MFMASET(A);
    LOADSET(A, 9);  MFMASET(B);
    LOADSET(B, 10); MFMASET(C);
    LOADSET(C, 11); MFMASET(A);
    LOADSET(A, 12); MFMASET(B);
    LOADSET(B, 13); MFMASET(C);
    LOADSET(C, 14); MFMASET(A);
    LOADSET(A, 15); MFMASET(B);
    LOADSET(B, 16); MFMASET(C);
    LOADSET(C, 17); MFMASET(A);
    MFMASET(B);
    MFMASET(C);
#undef LOADSET
#undef MFMASET

    // stores: h0+h1 cover the full 32-px row -> whole 128B lines per block;
    // after the 4-subtile loop each (co,row) 512B row is fully written.
    {
      const int gy = ty0 + wave;
      const int gx0 = tx0 + hi * 4;
      const int co0 = cob * 32 + lo;
      *(f32x4*)&out[(((size_t)n * CO + co0) * HH + gy) * WW + gx0] = acc00;
      *(f32x4*)&out[(((size_t)n * CO + co0) * HH + gy) * WW + gx0 + 16] = acc01;
      *(f32x4*)&out[(((size_t)n * CO + co0 + 16) * HH + gy) * WW + gx0] = acc10;
      *(f32x4*)&out[(((size_t)n * CO + co0 + 16) * HH + gy) * WW + gx0 + 16] = acc11;
    }
    __syncthreads();                         // protect halo/nbt overwrite
  }
}

// ================= SAFE PATH (Round-2 proven, 705 KB ws) =================
__global__ __launch_bounds__(256) void prep_kernel_safe(
    const float* __restrict__ in, const float* __restrict__ w,
    unsigned short* __restrict__ ws_w, float* __restrict__ ws_T) {
  const int bid = blockIdx.x, tid = threadIdx.x;
  if (bid < 288) {
    const int el = bid * 256 + tid;
    const int tap = el >> 13;
    const int rem = el & 8191;
    const int co = rem >> 6, ic = rem & 63;
    const int ky = (tap / 3) * 2, kx = (tap % 3) * 2;
    ws_w[el] = f2bf(w[(co * 64 + ic) * 25 + ky * 5 + kx]);
  } else {
    const int p = (bid - 288) * 256 + tid;
    const int n = p >> 14;
    const int yx = p & 16383;
    const float* base = in + (size_t)n * CI * (HH * WW) + yx;
    float s = 0.f;
    #pragma unroll
    for (int ic = 0; ic < CI; ++ic) s += base[ic * (HH * WW)];
    ws_T[p] = s;
  }
}

#define SHR 12
#define SHC 36
#define SNPOS (SHR * SHC)

__global__ __launch_bounds__(256, 2) void conv_kernel_safe(
    const float* __restrict__ in, const unsigned short* __restrict__ ws_w,
    const float* __restrict__ ws_T, float* __restrict__ out) {
  __shared__ short8 in_lds[SNPOS * 8];
  __shared__ float T_lds[SNPOS];

  const int tid = threadIdx.x;
  const int t = blockIdx.x;
  const int n = blockIdx.y;
  const int ty0 = (t >> 2) * 8;
  const int tx0 = (t & 3) * 32;

  for (int e = tid; e < SNPOS * 8; e += 256) {
    const int slot = e / SNPOS;
    const int pos = e - slot * SNPOS;
    const int r = pos / SHC, c = pos - r * SHC;
    const int gy = ty0 + r - 2, gx = tx0 + c - 2;
    const bool ok = (gy >= 0 && gy < HH && gx >= 0 && gx < WW);
    const long off = ((long)(n * CI + slot * 8) * HH + gy) * WW + gx;
    short8 pk;
    #pragma unroll
    for (int j = 0; j < 8; ++j) {
      const float v = ok ? in[off + (long)j * (HH * WW)] : 0.f;
      pk[j] = (short)f2bf(v);
    }
    in_lds[pos * 8 + (slot ^ (pos & 7))] = pk;
  }
  for (int e = tid; e < SNPOS; e += 256) {
    const int r = e / SHC, c = e - r * SHC;
    const int gy = ty0 + r - 2, gx = tx0 + c - 2;
    T_lds[e] = (gy >= 0 && gy < HH && gx >= 0 && gx < WW)
                   ? ws_T[((size_t)n * HH + gy) * WW + gx] : 0.f;
  }
  __syncthreads();

  const int wave = tid >> 6;
  const int lane = tid & 63;
  const int lo = lane & 15;
  const int hi = lane >> 4;

  int py[4], pxc[4];
  #pragma unroll
  for (int f = 0; f < 4; ++f) {
    const int pb = wave * 64 + f * 16;
    py[f] = pb >> 5;
    pxc[f] = (pb & 31) + lo;
  }

  f32x4 acc[8][4];
  #pragma unroll
  for (int cb = 0; cb < 8; ++cb)
    #pragma unroll
    for (int f = 0; f < 4; ++f) acc[cb][f] = (f32x4){0.f, 0.f, 0.f, 0.f};

  const short8* wsv = (const short8*)ws_w;

  #pragma unroll
  for (int tap = 0; tap < 9; ++tap) {
    const int ty = (tap / 3) * 2, tx = (tap % 3) * 2;
    #pragma unroll
    for (int ks = 0; ks < 2; ++ks) {
      short8 bfrag[4];
      #pragma unroll
      for (int f = 0; f < 4; ++f) {
        const int pos = (py[f] + ty) * SHC + (pxc[f] + tx);
        bfrag[f] = in_lds[pos * 8 + ((ks * 4 + hi) ^ (pos & 7))];
      }
      #pragma unroll
      for (int cb = 0; cb < 8; ++cb) {
        const short8 afrag = wsv[(tap * 128 + cb * 16 + lo) * 8 + ks * 4 + hi];
        #pragma unroll
        for (int f = 0; f < 4; ++f)
          acc[cb][f] = __builtin_amdgcn_mfma_f32_16x16x32_bf16(
              afrag, bfrag[f], acc[cb][f], 0, 0, 0);
      }
    }
  }

  float nb[4];
  #pragma unroll
  for (int f = 0; f < 4; ++f) {
    float s = 0.f;
    #pragma unroll
    for (int ky = 0; ky < 5; ++ky)
      #pragma unroll
      for (int kx = 0; kx < 5; ++kx)
        if ((ky & 1) | (kx & 1))
          s += T_lds[(py[f] + ky) * SHC + (pxc[f] + kx)];
    nb[f] = s * MU;
  }

  #pragma unroll
  for (int cb = 0; cb < 8; ++cb) {
    #pragma unroll
    for (int f = 0; f < 4; ++f) {
      const int gy = ty0 + py[f];
      const int gx = tx0 + pxc[f];
      #pragma unroll
      for (int q = 0; q < 4; ++q) {
        const int co = cb * 16 + hi * 4 + q;
        out[(((size_t)n * CO + co) * HH + gy) * WW + gx] = acc[cb][f][q] + nb[f];
      }
    }
  }
}

extern "C" void kernel_launch(void* const* d_in, const int* in_sizes, int n_in,
                              void* d_out, int out_size, void* d_ws, size_t ws_size,
                              hipStream_t stream) {
  const float* in = (const float*)d_in[0];
  const float* w  = (const float*)d_in[1];
  float* out = (float*)d_out;
  unsigned short* ws_w = (unsigned short*)d_ws;

  if (ws_size >= WS_TOTAL) {
    float* ws_T = (float*)((char*)d_ws + WS_T_OFF);
    short8* ws_x = (short8*)((char*)d_ws + WS_X_OFF);
    float* ws_nb = (float*)((char*)d_ws + WS_NB_OFF);
    prep_kernel<<<dim3(556), 256, 0, stream>>>(in, w, ws_w, ws_T, ws_x);
    nb_kernel<<<dim3(512), 256, 0, stream>>>(ws_T, ws_nb);
    conv_kernel<<<dim3(1024), 256, 0, stream>>>(
        ws_w, ws_nb, (const unsigned short*)ws_x, out);
  } else {
    float* ws_T = (float*)((char*)d_ws + WS_W_BYTES);
    prep_kernel_safe<<<dim3(288 + 512), 256, 0, stream>>>(in, w, ws_w, ws_T);
    conv_kernel_safe<<<dim3(64, NN), 256, 0, stream>>>(in, ws_w, ws_T, out);
  }
}

// Round 21
// 45.012 us; speedup vs baseline: 2.0868x; 1.0121x over previous
//
#include <hip/hip_runtime.h>

typedef short short8 __attribute__((ext_vector_type(8)));
typedef float f32x4 __attribute__((ext_vector_type(4)));

#define NN 8
#define CI 64
#define CO 128
#define HH 128
#define WW 128
#define PH 132             // padded (2-halo each side)
#define PW 132
#define MU 0.033333333333333333f

#define WS_W_BYTES (9 * 128 * 64 * 2)        // 147456
#define WS_T_OFF   WS_W_BYTES
#define WS_T_BYTES (NN * PH * PW * 4)        // 557568
#define WS_X_OFF   (WS_T_OFF + WS_T_BYTES)   // 705024
#define WS_X_BYTES ((size_t)NN * PH * PW * CI * 2)   // 17842176
#define WS_NB_OFF  (WS_X_OFF + WS_X_BYTES)   // 18547200
#define WS_TOTAL   (WS_NB_OFF + WS_T_BYTES)  // ~19.1 MB

__device__ __forceinline__ unsigned short f2bf(float f) {
  unsigned u = __float_as_uint(f);
  u += 0x7fffu + ((u >> 16) & 1u);     // round-to-nearest-even
  return (unsigned short)(u >> 16);
}

__device__ __forceinline__ void g2lds16(const void* g, void* l) {
  __builtin_amdgcn_global_load_lds(
      (const __attribute__((address_space(1))) unsigned int*)g,
      (__attribute__((address_space(3))) unsigned int*)l, 16, 0, 0);
}
__device__ __forceinline__ void g2lds4(const void* g, void* l) {
  __builtin_amdgcn_global_load_lds(
      (const __attribute__((address_space(1))) unsigned int*)g,
      (__attribute__((address_space(3))) unsigned int*)l, 4, 0, 0);
}

// ================= FAST PATH =================
// prep: bf16 NHWC padded repack + channel-sum plane T + weights (coalesced
// layout: ws_w[(tap*16 + cb*2 + ks)*64 + lane] short8, lane=hi*16+lo holds
// w[co=cb*16+lo][ic=ks*32+hi*8+j], even taps only). ws_x is PLAIN NHWC
// [n][y][x][ic] bf16 (128 B per pixel; the lx XOR pair cancels).
__global__ __launch_bounds__(256) void prep_kernel(
    const float* __restrict__ in, const float* __restrict__ w,
    unsigned short* __restrict__ ws_w, float* __restrict__ ws_T,
    short8* __restrict__ ws_x) {
  const int b = blockIdx.x, tid = threadIdx.x;
  if (b < 512) {
    __shared__ short8 lx[256][8];            // [px][slot^(px&7)]
    const int n = b >> 6, pair = b & 63;
    const int px = tid;
    const int r = pair * 2 + (px >> 7), x = px & 127;
    const float* src = in + ((size_t)(n * CI) * HH + r) * WW + x;
    float tsum = 0.f;
    #pragma unroll
    for (int g = 0; g < 8; ++g) {
      short8 pk;
      #pragma unroll
      for (int j = 0; j < 8; ++j) {
        const float v = src[(size_t)(g * 8 + j) * (HH * WW)];
        tsum += v;
        pk[j] = (short)f2bf(v);
      }
      lx[px][g ^ (px & 7)] = pk;
    }
    ws_T[(n * PH + r + 2) * PW + (x + 2)] = tsum;
    __syncthreads();
    #pragma unroll
    for (int it = 0; it < 8; ++it) {         // coalesced NHWC store, 16B/lane
      const int G = it * 256 + tid;
      const int px2 = G >> 3, g2 = G & 7;
      const int r2 = pair * 2 + (px2 >> 7), x2 = px2 & 127;
      ws_x[((size_t)(n * PH + r2 + 2) * PW + (x2 + 2)) * 8 + g2] =
          lx[px2][g2 ^ (px2 & 7)];
    }
  } else if (b < 520) {                      // zero the padded borders
    const int n = b - 512;
    const short8 z = {0, 0, 0, 0, 0, 0, 0, 0};
    for (int e = tid; e < 1040 * 8; e += 256) {
      const int px = e >> 3, g = e & 7;
      int y, x;
      if (px < 528) { const int r4 = px / 132; y = (r4 < 2) ? r4 : r4 + 128; x = px - r4 * 132; }
      else { const int q = px - 528; const int c4 = q >> 7; x = (c4 < 2) ? c4 : c4 + 128; y = 2 + (q & 127); }
      ws_x[((size_t)(n * PH + y) * PW + x) * 8 + g] = z;
    }
    for (int e = tid; e < 1040; e += 256) {
      int y, x;
      if (e < 528) { const int r4 = e / 132; y = (r4 < 2) ? r4 : r4 + 128; x = e - r4 * 132; }
      else { const int q = e - 528; const int c4 = q >> 7; x = (c4 < 2) ? c4 : c4 + 128; y = 2 + (q & 127); }
      ws_T[(n * PH + y) * PW + x] = 0.f;
    }
  } else {                                   // weights, coalesced MFMA layout
    const int el = (b - 520) * 256 + tid;    // 0..9215 short8 elements
    const int lane = el & 63;
    const int idx = el >> 6;                 // 0..143 = tap*16 + cb*2 + ks
    const int ks = idx & 1, cb = (idx >> 1) & 7, tap = idx >> 4;
    const int lo = lane & 15, hi = lane >> 4;
    const int ky = (tap / 3) * 2, kx = (tap % 3) * 2;
    const float* wp = w + (size_t)((cb * 16 + lo) * 64 + ks * 32 + hi * 8) * 25
                        + ky * 5 + kx;
    short8 pk;
    #pragma unroll
    for (int j = 0; j < 8; ++j) pk[j] = (short)f2bf(wp[j * 25]);
    ((short8*)ws_w)[el] = pk;
  }
}

// nb: per-pixel neighbor plane, COMPACT [n][128][128] (16B-aligned reads)
__global__ __launch_bounds__(256) void nb_kernel(
    const float* __restrict__ ws_T, float* __restrict__ ws_nb) {
  const int p = blockIdx.x * 256 + threadIdx.x;   // 131072 interior pixels
  const int n = p >> 14, yx = p & 16383;
  const int y = yx >> 7, x = yx & 127;
  const float* Tb = ws_T + (size_t)(n * PH + y) * PW + x;
  float s = 0.f;
  #pragma unroll
  for (int ky = 0; ky < 5; ++ky)
    #pragma unroll
    for (int kx = 0; kx < 5; ++kx)
      if ((ky & 1) | (kx & 1)) s += Tb[ky * PW + kx];
  ws_nb[(size_t)p] = s * MU;
}

// conv v12: v11 (XCD-pinned n=bid&7, 4-row strip, 3-deep af pipeline) +
// WEIGHTS IN REGISTERS: W[36] statically-indexed (fully unrolled -> regs),
// amdgpu_waves_per_eu(2,2) pins the 256-VGPR budget (R16 lesson: (256,2)
// launch_bounds alone lets the compiler cap at 128 and spill). Inner loop
// LDS reads drop 4->2 per 4 MFMAs: per-CU ds_read_b128 ~4608->~2304,
// removing the ~23us LDS-pipe wall the R13/R20 model identified.
__global__ __launch_bounds__(256)
__attribute__((amdgpu_waves_per_eu(2, 2)))
void conv_kernel(
    const unsigned short* __restrict__ ws_w, const float* __restrict__ ws_nb,
    const unsigned short* __restrict__ ws_x, float* __restrict__ out) {
  __shared__ short8 halo[288 * 8];     // 36864 B: 8 rows x 36 cols, swizzled
  __shared__ float  nbt[128];          // 512 B: 4 rows x 32 cols

  const int tid = threadIdx.x;
  const int wave = tid >> 6, lane = tid & 63;
  const int bid = blockIdx.x;          // 1024 = (strip*4 + quarter)*8 + n
  const int n = bid & 7;
  const int rest = bid >> 3;
  const int cob = rest & 3;            // co-quarter
  const int ty0 = (rest >> 2) * 4;     // 32 y-strips of 4 rows
  const int lo = lane & 15, hi = lane >> 4;

  // quarter weights -> registers once (36 coalesced b128, L2-hot; static idx)
  const short8* wsv = (const short8*)ws_w;
  short8 W[36];                        // [tap*4 + cbl*2 + ks]
  #pragma unroll
  for (int k = 0; k < 36; ++k)
    W[k] = wsv[((k >> 2) * 16 + cob * 4 + (k & 3)) * 64 + lane];

  for (int j = 0; j < 4; ++j) {
    const int tx0 = j * 32;                  // x-subtiles of our 4-row strip

    // halo DMA: 36 x 1KB chunks (9 per wave), source pre-swizzled
    for (int k = wave; k < 36; k += 4) {
      const int pos = k * 8 + (lane >> 3);
      const int r = pos / 36, c = pos - r * 36;
      const int chunk = (lane & 7) ^ (pos & 7);
      const unsigned short* g =
          ws_x + ((size_t)(n * PH + ty0 + r) * PW + (tx0 + c)) * 64 + chunk * 8;
      g2lds16(g, (char*)halo + k * 1024);
    }
    if (wave < 2) {                          // nb tile (compact plane)
      const float* g = ws_nb
          + (size_t)((n * 128 + ty0 + 2 * wave + (lane >> 5)) * 128)
          + tx0 + (lane & 31);
      g2lds4(g, (char*)nbt + wave * 256);
    }
    __syncthreads();                         // drains vmcnt (DMA complete)

    // acc init from NB (rows=px after operand swap); wave owns row `wave`
    const f32x4 nbv0 = *(const f32x4*)&nbt[wave * 32 + 0  + hi * 4];
    const f32x4 nbv1 = *(const f32x4*)&nbt[wave * 32 + 16 + hi * 4];
    f32x4 acc00 = nbv0, acc01 = nbv1;        // cbl0: h0, h1
    f32x4 acc10 = nbv0, acc11 = nbv1;        // cbl1: h0, h1

    short8 Aaf0, Aaf1;
    short8 Baf0, Baf1;
    short8 Caf0, Caf1;

#define LOADSET(P, K) { \
      constexpr int tap_ = (K) >> 1, ks_ = (K) & 1; \
      constexpr int ty_ = (tap_ / 3) * 2, tx_ = (tap_ % 3) * 2; \
      const int p0_ = (wave + ty_) * 36 + (lo + tx_); \
      const int p1_ = p0_ + 16; \
      P##af0 = halo[p0_ * 8 + ((ks_ * 4 + hi) ^ (p0_ & 7))]; \
      P##af1 = halo[p1_ * 8 + ((ks_ * 4 + hi) ^ (p1_ & 7))]; \
    }
#define MFMASET(P, K) { \
      constexpr int tap_ = (K) >> 1, ks_ = (K) & 1; \
      acc00 = __builtin_amdgcn_mfma_f32_16x16x32_bf16(P##af0, W[tap_ * 4 + 0 + ks_], acc00, 0, 0, 0); \
      acc01 = __builtin_amdgcn_mfma_f32_16x16x32_bf16(P##af1, W[tap_ * 4 + 0 + ks_], acc01, 0, 0, 0); \
      acc10 = __builtin_amdgcn_mfma_f32_16x16x32_bf16(P##af0, W[tap_ * 4 + 2 + ks_], acc10, 0, 0, 0); \
      acc11 = __builtin_amdgcn_mfma_f32_16x16x32_bf16(P##af1, W[tap_ * 4 + 2 + ks_], acc11, 0, 0, 0); \
    }

    LOADSET(A, 0); LOADSET(B, 1);
    LOADSET(C, 2);  MFMASET(A, 0);
    LOADSET(A, 3);  MFMASET(B, 1);
    LOADSET(B, 4);  MFMASET(C, 2);
    LOADSET(C, 5);  MFMASET(A, 3);
    LOADSET(A, 6);  MFMASET(B, 4);
    LOADSET(B, 7);  MFMASET(C, 5);
    LOADSET(C, 8);  MFMASET(A, 6);
    LOADSET(A, 9);  MFMASET(B, 7);
    LOADSET(B, 10); MFMASET(C, 8);
    LOADSET(C, 11); MFMASET(A, 9);
    LOADSET(A, 12); MFMASET(B, 10);
    LOADSET(B, 13); MFMASET(C, 11);
    LOADSET(C, 14); MFMASET(A, 12);
    LOADSET(A, 15); MFMASET(B, 13);
    LOADSET(B, 16); MFMASET(C, 14);
    LOADSET(C, 17); MFMASET(A, 15);
    MFMASET(B, 16);
    MFMASET(C, 17);
#undef LOADSET
#undef MFMASET

    // stores: h0+h1 cover the full 32-px row -> whole 128B lines per block;
    // after the 4-subtile loop each (co,row) 512B row is fully written.
    {
      const int gy = ty0 + wave;
      const int gx0 = tx0 + hi * 4;
      const int co0 = cob * 32 + lo;
      *(f32x4*)&out[(((size_t)n * CO + co0) * HH + gy) * WW + gx0] = acc00;
      *(f32x4*)&out[(((size_t)n * CO + co0) * HH + gy) * WW + gx0 + 16] = acc01;
      *(f32x4*)&out[(((size_t)n * CO + co0 + 16) * HH + gy) * WW + gx0] = acc10;
      *(f32x4*)&out[(((size_t)n * CO + co0 + 16) * HH + gy) * WW + gx0 + 16] = acc11;
    }
    __syncthreads();                         // protect halo/nbt overwrite
  }
}

// ================= SAFE PATH (Round-2 proven, 705 KB ws) =================
__global__ __launch_bounds__(256) void prep_kernel_safe(
    const float* __restrict__ in, const float* __restrict__ w,
    unsigned short* __restrict__ ws_w, float* __restrict__ ws_T) {
  const int bid = blockIdx.x, tid = threadIdx.x;
  if (bid < 288) {
    const int el = bid * 256 + tid;
    const int tap = el >> 13;
    const int rem = el & 8191;
    const int co = rem >> 6, ic = rem & 63;
    const int ky = (tap / 3) * 2, kx = (tap % 3) * 2;
    ws_w[el] = f2bf(w[(co * 64 + ic) * 25 + ky * 5 + kx]);
  } else {
    const int p = (bid - 288) * 256 + tid;
    const int n = p >> 14;
    const int yx = p & 16383;
    const float* base = in + (size_t)n * CI * (HH * WW) + yx;
    float s = 0.f;
    #pragma unroll
    for (int ic = 0; ic < CI; ++ic) s += base[ic * (HH * WW)];
    ws_T[p] = s;
  }
}

#define SHR 12
#define SHC 36
#define SNPOS (SHR * SHC)

__global__ __launch_bounds__(256, 2) void conv_kernel_safe(
    const float* __restrict__ in, const unsigned short* __restrict__ ws_w,
    const float* __restrict__ ws_T, float* __restrict__ out) {
  __shared__ short8 in_lds[SNPOS * 8];
  __shared__ float T_lds[SNPOS];

  const int tid = threadIdx.x;
  const int t = blockIdx.x;
  const int n = blockIdx.y;
  const int ty0 = (t >> 2) * 8;
  const int tx0 = (t & 3) * 32;

  for (int e = tid; e < SNPOS * 8; e += 256) {
    const int slot = e / SNPOS;
    const int pos = e - slot * SNPOS;
    const int r = pos / SHC, c = pos - r * SHC;
    const int gy = ty0 + r - 2, gx = tx0 + c - 2;
    const bool ok = (gy >= 0 && gy < HH && gx >= 0 && gx < WW);
    const long off = ((long)(n * CI + slot * 8) * HH + gy) * WW + gx;
    short8 pk;
    #pragma unroll
    for (int j = 0; j < 8; ++j) {
      const float v = ok ? in[off + (long)j * (HH * WW)] : 0.f;
      pk[j] = (short)f2bf(v);
    }
    in_lds[pos * 8 + (slot ^ (pos & 7))] = pk;
  }
  for (int e = tid; e < SNPOS; e += 256) {
    const int r = e / SHC, c = e - r * SHC;
    const int gy = ty0 + r - 2, gx = tx0 + c - 2;
    T_lds[e] = (gy >= 0 && gy < HH && gx >= 0 && gx < WW)
                   ? ws_T[((size_t)n * HH + gy) * WW + gx] : 0.f;
  }
  __syncthreads();

  const int wave = tid >> 6;
  const int lane = tid & 63;
  const int lo = lane & 15;
  const int hi = lane >> 4;

  int py[4], pxc[4];
  #pragma unroll
  for (int f = 0; f < 4; ++f) {
    const int pb = wave * 64 + f * 16;
    py[f] = pb >> 5;
    pxc[f] = (pb & 31) + lo;
  }

  f32x4 acc[8][4];
  #pragma unroll
  for (int cb = 0; cb < 8; ++cb)
    #pragma unroll
    for (int f = 0; f < 4; ++f) acc[cb][f] = (f32x4){0.f, 0.f, 0.f, 0.f};

  const short8* wsv = (const short8*)ws_w;

  #pragma unroll
  for (int tap = 0; tap < 9; ++tap) {
    const int ty = (tap / 3) * 2, tx = (tap % 3) * 2;
    #pragma unroll
    for (int ks = 0; ks < 2; ++ks) {
      short8 bfrag[4];
      #pragma unroll
      for (int f = 0; f < 4; ++f) {
        const int pos = (py[f] + ty) * SHC + (pxc[f] + tx);
        bfrag[f] = in_lds[pos * 8 + ((ks * 4 + hi) ^ (pos & 7))];
      }
      #pragma unroll
      for (int cb = 0; cb < 8; ++cb) {
        const short8 afrag = wsv[(tap * 128 + cb * 16 + lo) * 8 + ks * 4 + hi];
        #pragma unroll
        for (int f = 0; f < 4; ++f)
          acc[cb][f] = __builtin_amdgcn_mfma_f32_16x16x32_bf16(
              afrag, bfrag[f], acc[cb][f], 0, 0, 0);
      }
    }
  }

  float nb[4];
  #pragma unroll
  for (int f = 0; f < 4; ++f) {
    float s = 0.f;
    #pragma unroll
    for (int ky = 0; ky < 5; ++ky)
      #pragma unroll
      for (int kx = 0; kx < 5; ++kx)
        if ((ky & 1) | (kx & 1))
          s += T_lds[(py[f] + ky) * SHC + (pxc[f] + kx)];
    nb[f] = s * MU;
  }

  #pragma unroll
  for (int cb = 0; cb < 8; ++cb) {
    #pragma unroll
    for (int f = 0; f < 4; ++f) {
      const int gy = ty0 + py[f];
      const int gx = tx0 + pxc[f];
      #pragma unroll
      for (int q = 0; q < 4; ++q) {
        const int co = cb * 16 + hi * 4 + q;
        out[(((size_t)n * CO + co) * HH + gy) * WW + gx] = acc[cb][f][q] + nb[f];
      }
    }
  }
}

extern "C" void kernel_launch(void* const* d_in, const int* in_sizes, int n_in,
                              void* d_out, int out_size, void* d_ws, size_t ws_size,
                              hipStream_t stream) {
  const float* in = (const float*)d_in[0];
  const float* w  = (const float*)d_in[1];
  float* out = (float*)d_out;
  unsigned short* ws_w = (unsigned short*)d_ws;

  if (ws_size >= WS_TOTAL) {
    float* ws_T = (float*)((char*)d_ws + WS_T_OFF);
    short8* ws_x = (short8*)((char*)d_ws + WS_X_OFF);
    float* ws_nb = (float*)((char*)d_ws + WS_NB_OFF);
    prep_kernel<<<dim3(556), 256, 0, stream>>>(in, w, ws_w, ws_T, ws_x);
    nb_kernel<<<dim3(512), 256, 0, stream>>>(ws_T, ws_nb);
    conv_kernel<<<dim3(1024), 256, 0, stream>>>(
        ws_w, ws_nb, (const unsigned short*)ws_x, out);
  } else {
    float* ws_T = (float*)((char*)d_ws + WS_W_BYTES);
    prep_kernel_safe<<<dim3(288 + 512), 256, 0, stream>>>(in, w, ws_w, ws_T);
    conv_kernel_safe<<<dim3(64, NN), 256, 0, stream>>>(in, ws_w, ws_T, out);
  }
}